// Round 9
// baseline (926.827 us; speedup 1.0000x reference)
//
#include <hip/hip_runtime.h>
#include <math.h>

#define NTOK 65536   // B*T = 8*8192
#define T_   8192
#define C_   512

typedef short short8 __attribute__((ext_vector_type(8)));
typedef float f32x4  __attribute__((ext_vector_type(4)));

#define GLDS(gp, lp) __builtin_amdgcn_global_load_lds( \
    (__attribute__((address_space(1))) void*)(void*)(gp), \
    (__attribute__((address_space(3))) void*)(lp), 16, 0, 0)

__device__ __forceinline__ unsigned short f2bf(float f){
  unsigned x = __float_as_uint(f);
  x += 0x7fffu + ((x >> 16) & 1u);
  return (unsigned short)(x >> 16);
}
__device__ __forceinline__ float bflo(unsigned p){ return __uint_as_float(p << 16); }
__device__ __forceinline__ float bfhi(unsigned p){ return __uint_as_float(p & 0xffff0000u); }
__device__ __forceinline__ float bfs(unsigned short u){ return __uint_as_float(((unsigned)u) << 16); }
__device__ __forceinline__ unsigned pack2(float a, float b){
  return (unsigned)f2bf(a) | ((unsigned)f2bf(b) << 16);
}
// bijective XCD chunking (m204)
__device__ __forceinline__ int xcd_remap(int flat, int nwg){
  int q = nwg >> 3, r = nwg & 7;
  int xcd = flat & 7, idx = flat >> 3;
  return (xcd < r ? xcd * (q + 1) : r * (q + 1) + (xcd - r) * q) + idx;
}

// ---------------- weight prep ----------------
__global__ __launch_bounds__(256) void k_convert(const float* __restrict__ src,
                                                 unsigned short* __restrict__ dst, int n){
  int i = blockIdx.x * 256 + threadIdx.x;
  if (i < n) dst[i] = f2bf(src[i]);
}
__global__ __launch_bounds__(256) void k_transpose_t(const float* __restrict__ src,
                                                     unsigned short* __restrict__ dst,
                                                     int R, int S){
  __shared__ float tile[64][65];
  int ntS = S >> 6;
  int tr = blockIdx.x / ntS, ts = blockIdx.x - tr * ntS;
  int tx = threadIdx.x & 63, tg = threadIdx.x >> 6;
  #pragma unroll
  for (int rr = tg; rr < 64; rr += 4)
    tile[rr][tx] = src[(size_t)(tr * 64 + rr) * S + ts * 64 + tx];
  __syncthreads();
  #pragma unroll
  for (int rr = tg; rr < 64; rr += 4)
    dst[(size_t)(ts * 64 + rr) * R + tr * 64 + tx] = f2bf(tile[tx][rr]);
}

// ---------------- layernorm: one block per row (C=512) ----------------
__global__ __launch_bounds__(256) void k_ln(const float* __restrict__ x,
                                            const float* __restrict__ g,
                                            const float* __restrict__ b,
                                            unsigned* __restrict__ outbf){
  int row = blockIdx.x;
  int t = threadIdx.x;
  float2 v = ((const float2*)(x + (size_t)row * C_))[t];
  float s = v.x + v.y, ss = v.x * v.x + v.y * v.y;
  #pragma unroll
  for (int o = 32; o; o >>= 1){ s += __shfl_down(s, o); ss += __shfl_down(ss, o); }
  __shared__ float red[8];
  if ((t & 63) == 0){ red[t >> 6] = s; red[4 + (t >> 6)] = ss; }
  __syncthreads();
  float S = red[0] + red[1] + red[2] + red[3];
  float Q = red[4] + red[5] + red[6] + red[7];
  float mu  = S * (1.0f / C_);
  float var = Q * (1.0f / C_) - mu * mu;
  float rs = rsqrtf(var + 1e-5f);
  float y0 = (v.x - mu) * rs * g[2*t]   + b[2*t];
  float y1 = (v.y - mu) * rs * g[2*t+1] + b[2*t+1];
  outbf[(size_t)row * 256 + t] = pack2(y0, y1);
}

// ---------------- depthwise causal conv K=3, coalesced, chunk-local out ----------------
__global__ __launch_bounds__(256) void k_conv(const unsigned* __restrict__ xn,
                                              const float* __restrict__ w,
                                              const float* __restrict__ bias,
                                              unsigned* __restrict__ loc,
                                              int base){
  size_t idx = (size_t)blockIdx.x * 256 + threadIdx.x;
  size_t n = (idx >> 8) + (size_t)base;
  int cp = (int)(idx & 255);
  int t = (int)(n & (T_ - 1));
  unsigned v0 = xn[n * 256 + cp];
  unsigned v1 = (t >= 1) ? xn[(n - 1) * 256 + cp] : 0u;
  unsigned v2 = (t >= 2) ? xn[(n - 2) * 256 + cp] : 0u;
  int c = cp * 2;
  float r0 = bias[c]     + bflo(v0)*w[c*3+2] + bflo(v1)*w[c*3+1] + bflo(v2)*w[c*3+0];
  float r1 = bias[c + 1] + bfhi(v0)*w[c*3+5] + bfhi(v1)*w[c*3+4] + bfhi(v2)*w[c*3+3];
  loc[idx] = pack2(r0, r1);
}

// ---------------- in-place row softmax over M=512, bf16 ----------------
__global__ __launch_bounds__(256) void k_softmax_ip(unsigned* __restrict__ sw){
  int row = blockIdx.x;
  int t = threadIdx.x;
  unsigned p = sw[(size_t)row * 256 + t];
  float vx = bflo(p), vy = bfhi(p);
  float mx = fmaxf(vx, vy);
  #pragma unroll
  for (int o = 32; o; o >>= 1) mx = fmaxf(mx, __shfl_xor(mx, o));
  __shared__ float red[8];
  int w = t >> 6;
  if ((t & 63) == 0) red[w] = mx;
  __syncthreads();
  mx = fmaxf(fmaxf(red[0], red[1]), fmaxf(red[2], red[3]));
  float e0 = __expf(vx - mx), e1 = __expf(vy - mx);
  float s = e0 + e1;
  #pragma unroll
  for (int o = 32; o; o >>= 1) s += __shfl_xor(s, o);
  if ((t & 63) == 0) red[4 + w] = s;
  __syncthreads();
  float inv = 1.0f / (red[4] + red[5] + red[6] + red[7]);
  sw[(size_t)row * 256 + t] = pack2(e0 * inv, e1 * inv);
}

// =================== 128x128 bf16 GEMM, BK=64, 8 waves, 2 blocks/CU ===================
// RACE-FREE depth-1 schedule (R8 post-mortem): phase t computes buf b=t&1 and stages
// tile t+1 ONLY into buf b^1. WAR: buf b^1's reads completed before the previous
// phase's MM (per-wave lgkmcnt(0)) and all waves crossed that phase's end barrier
// before any wave issues this phase's stages. RAW: VMW0 before end barrier ensures
// staged data landed before next phase reads it. No same-buffer same-phase stages.
// T2 swizzle: pre-swizzled global source col + same XOR on every ds_read.
#define PH_PRE  { __builtin_amdgcn_s_barrier(); \
                  asm volatile("s_waitcnt lgkmcnt(0)" ::: "memory"); \
                  __builtin_amdgcn_sched_barrier(0); }
#define PH_END  __builtin_amdgcn_s_barrier();
#define VMW0    asm volatile("s_waitcnt vmcnt(0)" ::: "memory");

template<int EPI, int K, int N>
__global__ __launch_bounds__(512, 4) void k_g128(const unsigned short* __restrict__ A,
                                                 const unsigned short* __restrict__ Bt,
                                                 void* __restrict__ out,
                                                 const float* __restrict__ bias,
                                                 const float* __restrict__ add){
  __shared__ char smem[65536];
  const int tid  = threadIdx.x;
  const int lane = tid & 63;
  const int w    = tid >> 6;
  const int wr   = w >> 2, wc = w & 3;      // 2M x 4N waves; wave tile 64 x 32
  const int gx   = gridDim.x;
  const int nwg  = gx * gridDim.y;
  const int wgid = xcd_remap(blockIdx.y * gx + blockIdx.x, nwg);
  const long bcol = (long)(wgid % gx) * 128;
  const long brow = (long)(wgid / gx) * 128;
  const int lr = lane & 15;
  const int lk = (lane >> 4) * 16;
  const int srow  = tid >> 3;                               // 0..63 (8 thr/row)
  const int sbyte = ((tid & 7) * 16) ^ ((srow & 7) << 4);   // T2 pre-swizzled src col
  const unsigned swb = (unsigned)(w * 1024);
  const int rsw = (lr & 7) << 4;                            // T2 read-side XOR

  f32x4 acc[4][2];
  #pragma unroll
  for (int i = 0; i < 4; i++)
    #pragma unroll
    for (int j = 0; j < 2; j++){ f32x4 z = {0.f,0.f,0.f,0.f}; acc[i][j] = z; }

  const char* Ab = (const char*)(A + brow * (long)K);
  const char* Bb = (const char*)(Bt + bcol * (long)K);

  auto ST = [&](const char* g, int ldsoff, int row0, int kt){
    GLDS(g + ((long)(row0 + srow) * K + (long)kt * 64) * 2 + sbyte,
         smem + ldsoff + row0 * 128 + swb);
  };
  auto stA = [&](int b, int kt){ ST(Ab, b*16384, 0, kt); ST(Ab, b*16384, 64, kt); };
  auto stB = [&](int b, int kt){ ST(Bb, 32768+b*16384, 0, kt); ST(Bb, 32768+b*16384, 64, kt); };

  short8 afr[4][2], bfr[2][2];
  auto RD = [&](int b){
    #pragma unroll
    for (int mi = 0; mi < 4; mi++)
      #pragma unroll
      for (int kk = 0; kk < 2; kk++)
        afr[mi][kk] = *(const short8*)(smem + b*16384 +
            (wr*64 + mi*16 + lr) * 128 + ((kk*64 + lk) ^ rsw));
    #pragma unroll
    for (int ni = 0; ni < 2; ni++)
      #pragma unroll
      for (int kk = 0; kk < 2; kk++)
        bfr[ni][kk] = *(const short8*)(smem + 32768 + b*16384 +
            (wc*32 + ni*16 + lr) * 128 + ((kk*64 + lk) ^ rsw));
  };
  auto MM = [&](){
    __builtin_amdgcn_s_setprio(1);
    #pragma unroll
    for (int mi = 0; mi < 4; mi++)
      #pragma unroll
      for (int ni = 0; ni < 2; ni++)
        #pragma unroll
        for (int kk = 0; kk < 2; kk++)
          acc[mi][ni] = __builtin_amdgcn_mfma_f32_16x16x32_bf16(afr[mi][kk], bfr[ni][kk],
                                                                acc[mi][ni], 0, 0, 0);
    __builtin_amdgcn_s_setprio(0);
  };

  constexpr int nt = K >> 6;

  stA(0, 0); stB(0, 0);
  VMW0;
  __builtin_amdgcn_s_barrier();

  #pragma unroll 1
  for (int t = 0; t < nt; t++){
    const int b = t & 1;
    RD(b);
    if (t + 1 < nt){ stA(b ^ 1, t + 1); stB(b ^ 1, t + 1); }
    PH_PRE; MM();
    if (t + 1 < nt) { VMW0; }
    PH_END;
  }

  // epilogue: C/D layout col=lane&15, row=(lane>>4)*4+j
  const long rb = brow + wr * 64;
  const long cb = bcol + wc * 32;
  #pragma unroll
  for (int mi = 0; mi < 4; mi++){
    #pragma unroll
    for (int ni = 0; ni < 2; ni++){
      long rg0 = rb + mi * 16 + (lane >> 4) * 4;
      long cg  = cb + ni * 16 + lr;
      #pragma unroll
      for (int j = 0; j < 4; j++){
        long oi = (rg0 + j) * (long)N + cg;
        float v = acc[mi][ni][j];
        if (EPI == 1){
          ((unsigned short*)out)[oi] = f2bf(v);
        } else if (EPI == 3){
          v += bias[cg];
          v = 0.5f * v * (1.0f + erff(v * 0.70710678118654752f));
          ((unsigned short*)out)[oi] = f2bf(v);
        } else {
          v += bias[cg] + add[oi];
          ((float*)out)[oi] = v;
        }
      }
    }
  }
}

// ===== fused gates GEMM + sigmoid + combine + residual, 128-row tile, 2 blocks/CU =====
// Same race-free depth-1 schedule as k_g128 (stB = {BL unit, BG unit}).
// Tile: 128 rows x 64 cols of BOTH halves. 8 waves 4M x 2N.
// LDS 64KB: A[2][128][64] @0, BL[2][64][64] @32768 (buf b at b*8192), BG @49152.
__global__ __launch_bounds__(512, 4) void k_gc128(const unsigned short* __restrict__ A,
                                                  const unsigned short* __restrict__ Bt,
                                                  const float* __restrict__ gb,
                                                  const unsigned short* __restrict__ loc,
                                                  const unsigned short* __restrict__ ctx,
                                                  const float* __restrict__ x,
                                                  float* __restrict__ x2){
  __shared__ char smem[65536];
  const int tid  = threadIdx.x;
  const int lane = tid & 63;
  const int w    = tid >> 6;
  const int wr   = w >> 1, wc = w & 1;      // 4M x 2N waves
  const int gx   = gridDim.x;               // 8
  const int nwg  = gx * gridDim.y;
  const int wgid = xcd_remap(blockIdx.y * gx + blockIdx.x, nwg);
  const int  bcol = (wgid % gx) * 64;
  const long brow = (long)(wgid / gx) * 128;
  const int K = 512;
  const int lr = lane & 15;
  const int lk = (lane >> 4) * 16;
  const int srow  = tid >> 3;
  const int sbyte = ((tid & 7) * 16) ^ ((srow & 7) << 4);
  const unsigned swb = (unsigned)(w * 1024);
  const int rsw = (lr & 7) << 4;

  f32x4 acc[2][2][2];   // mi, ni, half
  #pragma unroll
  for (int i = 0; i < 2; i++)
    #pragma unroll
    for (int j = 0; j < 2; j++)
      #pragma unroll
      for (int h = 0; h < 2; h++){ f32x4 z = {0.f,0.f,0.f,0.f}; acc[i][j][h] = z; }

  const char* Ab  = (const char*)(A + brow * (long)K);
  const char* BbL = (const char*)(Bt + (long)bcol * K);
  const char* BbG = (const char*)(Bt + (long)(512 + bcol) * K);

  auto ST = [&](const char* g, int ldsoff, int row0, int kt){
    GLDS(g + ((long)(row0 + srow) * K + (long)kt * 64) * 2 + sbyte,
         smem + ldsoff + row0 * 128 + swb);
  };
  auto stA = [&](int b, int kt){ ST(Ab, b*16384, 0, kt); ST(Ab, b*16384, 64, kt); };
  auto stB = [&](int b, int kt){ ST(BbL, 32768+b*8192, 0, kt); ST(BbG, 49152+b*8192, 0, kt); };

  short8 afr[2][2], blf[2][2], bgf[2][2];
  auto RD = [&](int b){
    #pragma unroll
    for (int mi = 0; mi < 2; mi++)
      #pragma unroll
      for (int kk = 0; kk < 2; kk++)
        afr[mi][kk] = *(const short8*)(smem + b*16384 +
            (wr*32 + mi*16 + lr) * 128 + ((kk*64 + lk) ^ rsw));
    #pragma unroll
    for (int ni = 0; ni < 2; ni++)
      #pragma unroll
      for (int kk = 0; kk < 2; kk++){
        blf[ni][kk] = *(const short8*)(smem + 32768 + b*8192 +
            (wc*32 + ni*16 + lr) * 128 + ((kk*64 + lk) ^ rsw));
        bgf[ni][kk] = *(const short8*)(smem + 49152 + b*8192 +
            (wc*32 + ni*16 + lr) * 128 + ((kk*64 + lk) ^ rsw));
      }
  };
  auto MM = [&](){
    __builtin_amdgcn_s_setprio(1);
    #pragma unroll
    for (int mi = 0; mi < 2; mi++)
      #pragma unroll
      for (int ni = 0; ni < 2; ni++)
        #pragma unroll
        for (int kk = 0; kk < 2; kk++){
          acc[mi][ni][0] = __builtin_amdgcn_mfma_f32_16x16x32_bf16(afr[mi][kk], blf[ni][kk],
                                                                   acc[mi][ni][0], 0, 0, 0);
          acc[mi][ni][1] = __builtin_amdgcn_mfma_f32_16x16x32_bf16(afr[mi][kk], bgf[ni][kk],
                                                                   acc[mi][ni][1], 0, 0, 0);
        }
    __builtin_amdgcn_s_setprio(0);
  };

  constexpr int nt = 8;   // K=512

  stA(0, 0); stB(0, 0);
  VMW0;
  __builtin_amdgcn_s_barrier();

  #pragma unroll 1
  for (int t = 0; t < nt; t++){
    const int b = t & 1;
    RD(b);
    if (t + 1 < nt){ stA(b ^ 1, t + 1); stB(b ^ 1, t + 1); }
    PH_PRE; MM();
    if (t + 1 < nt) { VMW0; }
    PH_END;
  }

  const long rb = brow + wr * 32;
  const int  cb = bcol + wc * 32;
  #pragma unroll
  for (int mi = 0; mi < 2; mi++){
    #pragma unroll
    for (int ni = 0; ni < 2; ni++){
      long rg0 = rb + mi * 16 + (lane >> 4) * 4;
      int  cg  = cb + ni * 16 + lr;
      float bL = gb[cg], bG = gb[512 + cg];
      #pragma unroll
      for (int j = 0; j < 4; j++){
        long rg = rg0 + j;
        long oi = rg * 512 + cg;
        float vL = 1.0f / (1.0f + __expf(-(acc[mi][ni][0][j] + bL)));
        float vG = 1.0f / (1.0f + __expf(-(acc[mi][ni][1][j] + bG)));
        x2[oi] = x[oi] + vL * bfs(loc[oi]) + vG * bfs(ctx[oi]);
      }
    }
  }
}

// ---------------- launch ----------------
extern "C" void kernel_launch(void* const* d_in, const int* in_sizes, int n_in,
                              void* d_out, int out_size, void* d_ws, size_t ws_size,
                              hipStream_t stream){
  const float* x      = (const float*)d_in[0];
  const float* conv_w = (const float*)d_in[1];
  const float* conv_b = (const float*)d_in[2];
  const float* mb     = (const float*)d_in[3];
  const float* gate_w = (const float*)d_in[4];
  const float* gate_b = (const float*)d_in[5];
  const float* w1     = (const float*)d_in[6];
  const float* b1     = (const float*)d_in[7];
  const float* w2     = (const float*)d_in[8];
  const float* b2     = (const float*)d_in[9];
  const float* ln1g   = (const float*)d_in[10];
  const float* ln1b   = (const float*)d_in[11];
  const float* ln2g   = (const float*)d_in[12];
  const float* ln2b   = (const float*)d_in[13];

  char* ws = (char*)d_ws;
  const size_t MB = 1024ull * 1024ull;
  unsigned short* mb_bf = (unsigned short*)(ws + 0);
  unsigned short* mbT   = (unsigned short*)(ws + 512 * 1024);
  unsigned short* gwT   = (unsigned short*)(ws + 1 * MB);
  unsigned short* w1T   = (unsigned short*)(ws + 2 * MB);
  unsigned short* w2T   = (unsigned short*)(ws + 4 * MB);
  unsigned short* xn    = (unsigned short*)(ws + 8 * MB);   // 64MB; reused as h
  char* region = ws + 72 * MB;

  int S;
  if      (ws_size >= 264 * MB) S = 65536;
  else if (ws_size >= 120 * MB) S = 16384;
  else                          S = 4096;
  const int S2 = S / 2;
  const int NC  = NTOK / S;
  const int NC2 = NTOK / S2;

  unsigned short* loc_c = (unsigned short*)(region);
  unsigned short* ctx_c = (unsigned short*)(region + (size_t)S * 1024);
  unsigned short* sco_c = (unsigned short*)(region + (size_t)S * 2048);
  unsigned short* f1    = (unsigned short*)(region);

  // weight prep
  k_convert    <<<1024, 256, 0, stream>>>(mb, mb_bf, 512 * 512);
  k_transpose_t<<<  64, 256, 0, stream>>>(mb, mbT, 512, 512);
  k_transpose_t<<< 128, 256, 0, stream>>>(gate_w, gwT, 512, 1024);
  k_transpose_t<<< 256, 256, 0, stream>>>(w1, w1T, 512, 2048);
  k_transpose_t<<< 256, 256, 0, stream>>>(w2, w2T, 2048, 512);

  // LN1 -> xn (bf16, full)
  k_ln<<<NTOK, 256, 0, stream>>>(x, ln1g, ln1b, (unsigned*)xn);

  // middle phase, chunked over tokens
  for (int c = 0; c < NC; c++){
    const int base = c * S;
    const unsigned short* xnc = xn + (size_t)base * 512;
    k_conv<<<S, 256, 0, stream>>>((const unsigned*)xn, conv_w, conv_b,
                                  (unsigned*)loc_c, base);
    // scores = xn @ mb^T (bf16)
    k_g128<1, 512, 512><<<dim3(4, S / 128), 512, 0, stream>>>(xnc, mb_bf, sco_c,
                                                              nullptr, nullptr);
    k_softmax_ip<<<S, 256, 0, stream>>>((unsigned*)sco_c);
    // ctx = weights @ mb (bf16)
    k_g128<1, 512, 512><<<dim3(4, S / 128), 512, 0, stream>>>(sco_c, mbT, ctx_c,
                                                              nullptr, nullptr);
    // gates GEMM + sigmoid + combine + residual -> x2 (f32, into d_out)
    k_gc128<<<dim3(8, S / 128), 512, 0, stream>>>(xnc, gwT, gate_b,
                                                  loc_c, ctx_c,
                                                  x + (size_t)base * 512,
                                                  (float*)d_out + (size_t)base * 512);
  }

  // LN2: h = LN(x2) (bf16, reuse xn buffer)
  k_ln<<<NTOK, 256, 0, stream>>>((const float*)d_out, ln2g, ln2b, (unsigned*)xn);

  // FFN, chunked
  for (int c = 0; c < NC2; c++){
    const int base = c * S2;
    // f1 = gelu(h @ w1 + b1) (bf16)
    k_g128<3, 512, 2048><<<dim3(16, S2 / 128), 512, 0, stream>>>(xn + (size_t)base * 512,
                                                                 w1T, f1, b1, nullptr);
    // out = x2 + f1 @ w2 + b2 (f32, in-place per-element on d_out)
    k_g128<4, 2048, 512><<<dim3(4, S2 / 128), 512, 0, stream>>>(f1, w2T,
                                                                (float*)d_out + (size_t)base * 512,
                                                                b2,
                                                                (const float*)d_out + (size_t)base * 512);
  }
}